// Round 14
// baseline (838.877 us; speedup 1.0000x reference)
//
#include <hip/hip_runtime.h>
#include <math.h>

// GARNN: graph-attention GRU, B=16, N=512, U=64, SEQ=12, HORIZON=12, all f32.
// R14 = R13 (759us: two-stream batch-halves) scaled to FOUR streams x 4
// batches. 256-block dispatches (1 blk/CU) let up to 3 streams' kernels
// co-reside per CU (3-blk capacity) -> continuous CU feed while each stream's
// 25-dispatch chain advances independently. Kernels byte-identical to R7;
// decode maps XCD x -> batch bq+(x>>1) (2 XCDs/batch; per-XCD concurrent set
// = 4 batches ~ 2.6MB < 4MB L2). absmax must stay 1.525879e-05.

#define NB 16
#define NN 512
#define NU 64
#define CAP 128   // neighbor-list capacity (Bin(511,0.1) max << 128)
#define WPB 8     // waves (=nodes) per block
#define NSTREAMS 4

#define AS1 __attribute__((address_space(1)))
#define AS3 __attribute__((address_space(3)))

__device__ __forceinline__ void ld_lds16(float* lds_uniform, const float* g_perlane) {
#if __has_builtin(__builtin_amdgcn_global_load_lds)
  __builtin_amdgcn_global_load_lds((const AS1 unsigned int*)g_perlane,
                                   (AS3 unsigned int*)lds_uniform, 16, 0, 0);
#else
  int lane = threadIdx.x & 63;
  *(float4*)(lds_uniform + lane * 4) = *(const float4*)(g_perlane);
#endif
}

// Async-stage TB bytes of weights into sW. Wave w handles chunks c = w, w+8, ...
__device__ __forceinline__ void stage_weights(float* sW, const float* W, int TB,
                                              int w, int lane) {
  for (int c = w; c * 1024 < TB; c += WPB) {
    int off = c * 1024 + lane * 16;
    if (off < TB)
      ld_lds16((float*)((char*)sW + c * 1024), (const float*)((const char*)W + off));
  }
}

__device__ __forceinline__ float rlane(float v, int l) {
  return __int_as_float(__builtin_amdgcn_readlane(__float_as_int(v), l));
}
__device__ __forceinline__ int rlane_i(int v, int l) {
  return __builtin_amdgcn_readlane(v, l);
}
__device__ __forceinline__ float wave_max(float v) {
  #pragma unroll
  for (int s = 1; s < 64; s <<= 1) v = fmaxf(v, __shfl_xor(v, s));
  return v;
}
__device__ __forceinline__ float wave_sum(float v) {
  #pragma unroll
  for (int s = 1; s < 64; s <<= 1) v += __shfl_xor(v, s);
  return v;
}
__device__ __forceinline__ void wave_sum2(float& x, float& y) {
  #pragma unroll
  for (int s = 1; s < 64; s <<= 1) { x += __shfl_xor(x, s); y += __shfl_xor(y, s); }
}
__device__ __forceinline__ float fast_rcp(float x) {
#if __has_builtin(__builtin_amdgcn_rcpf)
  return __builtin_amdgcn_rcpf(x);
#else
  return 1.0f / x;
#endif
}
__device__ __forceinline__ float sigmoid_f(float x) {
  return fast_rcp(1.0f + __expf(-x));
}
__device__ __forceinline__ float tanh_f(float x) {
  return 1.0f - 2.0f * fast_rcp(__expf(2.0f * x) + 1.0f);
}

// Quarter-grid decode (256 blocks, 4 batches): XCD x = bx&7; batch =
// bq + (x>>1) (XCD pair per batch); node i from (k, x&1, wave). Bijective.
__device__ __forceinline__ void decode_q(int bx, int w, int bq, int& b, int& i) {
  int x = bx & 7, k = bx >> 3;               // k in [0,32)
  b = bq + (x >> 1);
  i = (((k << 1) | (x & 1)) << 3) | w;       // [0,512)
}

// Neighbor lists: mask[i][j] = adj[i][j] > 0.9 || i == j, ascending j.
// Pad tail [cnt, CAP) with j=i so gather loops run unpredicated (p=0 there).
__global__ __launch_bounds__(64) void k_adj(const float* __restrict__ adj,
                                            int* __restrict__ cnt,
                                            int* __restrict__ idx) {
  int i = blockIdx.x;
  int l = threadIdx.x;
  int base = 0;
  #pragma unroll
  for (int c = 0; c < 8; ++c) {
    int j = c * 64 + l;
    bool pred = (adj[i * NN + j] > 0.9f) || (j == i);
    unsigned long long m = __ballot(pred);
    int pos = base + __popcll(m & ((1ull << l) - 1ull));
    if (pred && pos < CAP) idx[i * CAP + pos] = j;
    base += __popcll(m);
  }
  int total = base > CAP ? CAP : base;
  for (int p = total + l; p < CAP; p += 64) idx[i * CAP + p] = i;  // pad
  if (l == 0) cnt[i] = total;
}

// Phase B: ru-attention -> r,u ; write u; h_c = [x, r*h] @ W_c; src_c/dst_c.
// EXACT R7 structure (depth-16 gather, (512,6)); bq selects batch quarter.
template <int DIN>
__global__ __launch_bounds__(512, 6) void k_phaseB(
    const int* __restrict__ cnt, const int* __restrict__ idx,
    const float* __restrict__ h_ru, const float* __restrict__ src_ru,
    const float* __restrict__ dst_ru, const float* __restrict__ b_ru,
    const float* __restrict__ h, const float* __restrict__ x_ptr,
    const float* __restrict__ W_c, const float* __restrict__ a_c,
    float* __restrict__ h_c, float* __restrict__ src_c,
    float* __restrict__ dst_c, float* __restrict__ u_buf, int bq) {
  constexpr int TB = (DIN + NU) * NU * 4;
  __shared__ float sW[(DIN + NU) * NU];
  __shared__ float sh[WPB * NU];    // per-wave r*h broadcast
  const int tid = threadIdx.x;
  const int w = tid >> 6, lane = tid & 63;

  stage_weights(sW, W_c, TB, w, lane);   // async; drained at the barrier below

  int b, i;
  decode_q(blockIdx.x, w, bq, b, i);
  const int base_bi = (b << 9) + i;
  const float* __restrict__ hrb = h_ru + ((size_t)b << 16);
  const float* __restrict__ drb = dst_ru + (b << 9);

  const int c_ = cnt[i];
  const float si = src_ru[base_bi];
  const int j0 = idx[(i << 7) + lane];
  const int j1 = idx[(i << 7) + 64 + lane];
  float e0 = -1e30f, e1 = -1e30f;
  if (lane < c_)      { float t = si + drb[j0]; e0 = t >= 0.f ? t : 0.2f * t; }
  if (lane + 64 < c_) { float t = si + drb[j1]; e1 = t >= 0.f ? t : 0.2f * t; }
  float m = wave_max(fmaxf(e0, e1));
  float p0 = (lane < c_) ? __expf(e0 - m) : 0.f;
  float p1 = (lane + 64 < c_) ? __expf(e1 - m) : 0.f;
  float inv = fast_rcp(wave_sum(p0 + p1));
  p0 *= inv; p1 *= inv;

  const int g0 = lane << 1;
  float A0 = 0.f, A1 = 0.f, B0 = 0.f, B1 = 0.f;
  const int cc = (c_ + 15) & ~15;
  for (int base = 0; base < cc; base += 16) {
    float2 hv[16];
    #pragma unroll
    for (int q = 0; q < 16; ++q) {
      int jj = base + q;
      int sl = jj & 63;
      int j = (jj < 64) ? rlane_i(j0, sl) : rlane_i(j1, sl);
      hv[q] = *(const float2*)(hrb + (j << 7) + g0);
    }
    #pragma unroll
    for (int q = 0; q < 16; ++q) {
      int jj = base + q;
      int sl = jj & 63;
      float pv = (jj < 64) ? rlane(p0, sl) : rlane(p1, sl);
      if (q & 1) { B0 = fmaf(pv, hv[q].x, B0); B1 = fmaf(pv, hv[q].y, B1); }
      else       { A0 = fmaf(pv, hv[q].x, A0); A1 = fmaf(pv, hv[q].y, A1); }
    }
  }
  A0 += B0; A1 += B1;

  const float2 br = *(const float2*)(b_ru + g0);
  const float ru0 = sigmoid_f(A0 + br.x);
  const float ru1 = sigmoid_f(A1 + br.y);

  if (lane < 32) {
    float2 hh = *(const float2*)(h + ((size_t)base_bi << 6) + g0);
    *(float2*)&sh[(w << 6) + g0] = make_float2(ru0 * hh.x, ru1 * hh.y);
  } else {
    *(float2*)(u_buf + ((size_t)base_bi << 6) + (g0 - 64)) = make_float2(ru0, ru1);
  }

  __syncthreads();   // drains async weight stage + sh visibility

  float acc;
  if (DIN == 2) {
    float2 xv = *(const float2*)(x_ptr + ((size_t)base_bi << 1));
    acc = xv.x * sW[lane];
    acc = fmaf(xv.y, sW[NU + lane], acc);
  } else {
    acc = x_ptr[base_bi] * sW[lane];
  }
  const float* __restrict__ sWh = sW + DIN * NU;
  const float* shw = sh + (w << 6);
  #pragma unroll
  for (int f2 = 0; f2 < 32; ++f2) {
    float2 rv = *(const float2*)(shw + 2 * f2);   // b64 broadcast
    acc = fmaf(rv.x, sWh[(2 * f2) * NU + lane], acc);
    acc = fmaf(rv.y, sWh[(2 * f2 + 1) * NU + lane], acc);
  }
  h_c[((size_t)base_bi << 6) + lane] = acc;
  float s0 = acc * a_c[lane];
  float s1 = acc * a_c[NU + lane];
  wave_sum2(s0, s1);
  if (lane == 0) { src_c[base_bi] = s0; dst_c[base_bi] = s1; }
}

// Phase A: c-attention -> c; h_new = u*h + (1-u)*c (UPD) or 0 (init);
// OUT: proj -> out+y_buf; DIN_NEXT>0: next cell h_ru = [x_next, h_new] @ W_ru.
// EXACT R7 structure; bq selects batch quarter.
template <int UPD, int DIN_NEXT, int XMODE, int OUT>
__global__ __launch_bounds__(512, 6) void k_phaseA(
    const int* __restrict__ cnt, const int* __restrict__ idx,
    const float* __restrict__ h_c, const float* __restrict__ src_c,
    const float* __restrict__ dst_c, const float* __restrict__ b_c,
    const float* __restrict__ u_buf, float* __restrict__ h,
    const float* __restrict__ proj_W, const float* __restrict__ proj_b,
    float* __restrict__ out_slice, float* __restrict__ y_buf,
    const float* __restrict__ x_ptr,
    const float* __restrict__ W_ru, const float* __restrict__ a_ru,
    float* __restrict__ h_ru, float* __restrict__ src_ru,
    float* __restrict__ dst_ru, int bq) {
  constexpr int SWN = (DIN_NEXT > 0) ? (DIN_NEXT + NU) * 128 : 1;
  constexpr int TB = (DIN_NEXT > 0) ? SWN * 4 : 0;
  __shared__ float sW[SWN];
  __shared__ float sh[WPB * NU];
  const int tid = threadIdx.x;
  const int w = tid >> 6, lane = tid & 63;

  if (DIN_NEXT > 0) stage_weights(sW, W_ru, TB, w, lane);  // async

  int b, i;
  decode_q(blockIdx.x, w, bq, b, i);
  const int base_bi = (b << 9) + i;

  float hn = 0.f;
  if (UPD) {
    const float* __restrict__ hcb = h_c + ((size_t)b << 15);
    const float* __restrict__ dcb = dst_c + (b << 9);
    const int c_ = cnt[i];
    const float si = src_c[base_bi];
    const int j0 = idx[(i << 7) + lane];
    const int j1 = idx[(i << 7) + 64 + lane];
    float e0 = -1e30f, e1 = -1e30f;
    if (lane < c_)      { float t = si + dcb[j0]; e0 = t >= 0.f ? t : 0.2f * t; }
    if (lane + 64 < c_) { float t = si + dcb[j1]; e1 = t >= 0.f ? t : 0.2f * t; }
    float m = wave_max(fmaxf(e0, e1));
    float p0 = (lane < c_) ? __expf(e0 - m) : 0.f;
    float p1 = (lane + 64 < c_) ? __expf(e1 - m) : 0.f;
    float inv = fast_rcp(wave_sum(p0 + p1));
    p0 *= inv; p1 *= inv;

    float A = 0.f, Bacc = 0.f;
    const int cc = (c_ + 15) & ~15;
    for (int base = 0; base < cc; base += 16) {
      float hv[16];
      #pragma unroll
      for (int q = 0; q < 16; ++q) {
        int jj = base + q;
        int sl = jj & 63;
        int j = (jj < 64) ? rlane_i(j0, sl) : rlane_i(j1, sl);
        hv[q] = hcb[(j << 6) + lane];
      }
      #pragma unroll
      for (int q = 0; q < 16; ++q) {
        int jj = base + q;
        int sl = jj & 63;
        float pv = (jj < 64) ? rlane(p0, sl) : rlane(p1, sl);
        if (q & 1) Bacc = fmaf(pv, hv[q], Bacc);
        else       A = fmaf(pv, hv[q], A);
      }
    }
    A += Bacc;
    const float cc_ = tanh_f(A + b_c[lane]);
    const float u = u_buf[((size_t)base_bi << 6) + lane];
    const float ho = h[((size_t)base_bi << 6) + lane];
    hn = fmaf(u, ho - cc_, cc_);   // u*ho + (1-u)*cc
  }
  h[((size_t)base_bi << 6) + lane] = hn;
  sh[(w << 6) + lane] = hn;        // wave-private broadcast buffer

  float y = 0.f;
  if (OUT) {
    float t = wave_sum(hn * proj_W[lane]);
    y = t + proj_b[0];
    if (lane == 0) { out_slice[base_bi] = y; y_buf[base_bi] = y; }
  }

  if (DIN_NEXT > 0) {
    __syncthreads();   // drains async weight stage; sh written above
    const int g0 = lane << 1;
    float a0, a1;
    if (XMODE == 0) {
      if (DIN_NEXT == 2) {
        float2 xv = *(const float2*)(x_ptr + ((size_t)base_bi << 1));
        a0 = xv.x * sW[g0];
        a1 = xv.x * sW[g0 + 1];
        a0 = fmaf(xv.y, sW[128 + g0], a0);
        a1 = fmaf(xv.y, sW[128 + g0 + 1], a1);
      } else {
        float xv = x_ptr[base_bi];
        a0 = xv * sW[g0]; a1 = xv * sW[g0 + 1];
      }
    } else if (XMODE == 2) {
      a0 = y * sW[g0]; a1 = y * sW[g0 + 1];
    } else {  // XMODE==1: decoder GO token (zeros)
      a0 = 0.f; a1 = 0.f;
    }
    const float* __restrict__ sWh = sW + DIN_NEXT * 128;
    const float* shw = sh + (w << 6);
    #pragma unroll
    for (int f2 = 0; f2 < 32; ++f2) {
      float2 hp = *(const float2*)(shw + 2 * f2);          // b64 broadcast
      float2 w0 = *(const float2*)(sWh + (2 * f2) * 128 + g0);
      float2 w1 = *(const float2*)(sWh + (2 * f2 + 1) * 128 + g0);
      a0 = fmaf(hp.x, w0.x, a0); a1 = fmaf(hp.x, w0.y, a1);
      a0 = fmaf(hp.y, w1.x, a0); a1 = fmaf(hp.y, w1.y, a1);
    }
    *(float2*)(h_ru + ((size_t)base_bi << 7) + g0) = make_float2(a0, a1);
    const float2 ar0 = *(const float2*)(a_ru + g0);
    const float2 ar1 = *(const float2*)(a_ru + 128 + g0);
    float s0 = a0 * ar0.x + a1 * ar0.y;
    float s1 = a0 * ar1.x + a1 * ar1.y;
    wave_sum2(s0, s1);
    if (lane == 0) { src_ru[base_bi] = s0; dst_ru[base_bi] = s1; }
  }
}

extern "C" void kernel_launch(void* const* d_in, const int* in_sizes, int n_in,
                              void* d_out, int out_size, void* d_ws, size_t ws_size,
                              hipStream_t stream) {
  (void)in_sizes; (void)n_in; (void)out_size; (void)ws_size;
  const float* inputs   = (const float*)d_in[0];
  const float* adj      = (const float*)d_in[1];
  const float* enc_W_ru = (const float*)d_in[2];
  const float* enc_a_ru = (const float*)d_in[3];
  const float* enc_b_ru = (const float*)d_in[4];
  const float* enc_W_c  = (const float*)d_in[5];
  const float* enc_a_c  = (const float*)d_in[6];
  const float* enc_b_c  = (const float*)d_in[7];
  const float* dec_W_ru = (const float*)d_in[8];
  const float* dec_a_ru = (const float*)d_in[9];
  const float* dec_b_ru = (const float*)d_in[10];
  const float* dec_W_c  = (const float*)d_in[11];
  const float* dec_a_c  = (const float*)d_in[12];
  const float* dec_b_c  = (const float*)d_in[13];
  const float* proj_W   = (const float*)d_in[14];
  const float* proj_b   = (const float*)d_in[15];
  float* out = (float*)d_out;

  char* ws = (char*)d_ws;
  int*   cnt    = (int*)ws;                    // 512*4        = 2048
  int*   idx    = (int*)(ws + 2048);           // 512*128*4    = 262144
  float* h      = (float*)(ws + 264192);       // 16*512*64*4  = 2097152
  float* h_ru   = (float*)(ws + 2361344);      // 16*512*128*4 = 4194304
  float* src_ru = (float*)(ws + 6555648);      // 32768
  float* dst_ru = (float*)(ws + 6588416);      // 32768
  float* h_c    = (float*)(ws + 6621184);      // 2097152
  float* src_c  = (float*)(ws + 8718336);      // 32768
  float* dst_c  = (float*)(ws + 8751104);      // 32768
  float* u_buf  = (float*)(ws + 8783872);      // 2097152
  float* y_buf  = (float*)(ws + 10881024);     // 32768 (end 10913792)

  // One-time side streams + events (resources only; no work-affecting state).
  static hipStream_t s2[NSTREAMS - 1] = {nullptr, nullptr, nullptr};
  static hipEvent_t evFork = nullptr;
  static hipEvent_t evJoin[NSTREAMS - 1] = {nullptr, nullptr, nullptr};
  if (s2[0] == nullptr) {
    for (int q = 0; q < NSTREAMS - 1; ++q) {
      hipStreamCreateWithFlags(&s2[q], hipStreamNonBlocking);
      hipEventCreateWithFlags(&evJoin[q], hipEventDisableTiming);
    }
    hipEventCreateWithFlags(&evFork, hipEventDisableTiming);
  }

  hipMemsetAsync(y_buf, 0, NB * NN * sizeof(float), stream);
  k_adj<<<NN, 64, 0, stream>>>(adj, cnt, idx);

  // Fork: side streams join the capture graph after k_adj + memset.
  hipEventRecord(evFork, stream);
  for (int q = 0; q < NSTREAMS - 1; ++q) hipStreamWaitEvent(s2[q], evFork, 0);

  const int GRID = (NB * NN) / (NSTREAMS * WPB);  // 256 blocks per dispatch

  for (int quarter = 0; quarter < NSTREAMS; ++quarter) {
    hipStream_t st = (quarter == 0) ? stream : s2[quarter - 1];
    const int bq = quarter * (NB / NSTREAMS);

    // init: h = 0, compute h_ru(x_0) with encoder weights
    k_phaseA<0, 2, 0, 0><<<GRID, 512, 0, st>>>(cnt, idx, h_c, src_c, dst_c,
        enc_b_c, u_buf, h, proj_W, proj_b, nullptr, y_buf,
        inputs, enc_W_ru, enc_a_ru, h_ru, src_ru, dst_ru, bq);

    for (int t = 0; t < 12; ++t) {
      k_phaseB<2><<<GRID, 512, 0, st>>>(cnt, idx, h_ru, src_ru, dst_ru, enc_b_ru,
          h, inputs + (size_t)t * NB * NN * 2, enc_W_c, enc_a_c,
          h_c, src_c, dst_c, u_buf, bq);
      if (t < 11)
        k_phaseA<1, 2, 0, 0><<<GRID, 512, 0, st>>>(cnt, idx, h_c, src_c, dst_c,
            enc_b_c, u_buf, h, proj_W, proj_b, nullptr, y_buf,
            inputs + (size_t)(t + 1) * NB * NN * 2, enc_W_ru, enc_a_ru,
            h_ru, src_ru, dst_ru, bq);
      else  // last encoder cell: prepare decoder cell 0 (x = GO = zeros)
        k_phaseA<1, 1, 1, 0><<<GRID, 512, 0, st>>>(cnt, idx, h_c, src_c, dst_c,
            enc_b_c, u_buf, h, proj_W, proj_b, nullptr, y_buf,
            nullptr, dec_W_ru, dec_a_ru, h_ru, src_ru, dst_ru, bq);
    }

    for (int k = 0; k < 12; ++k) {
      k_phaseB<1><<<GRID, 512, 0, st>>>(cnt, idx, h_ru, src_ru, dst_ru, dec_b_ru,
          h, y_buf, dec_W_c, dec_a_c, h_c, src_c, dst_c, u_buf, bq);
      if (k < 11)
        k_phaseA<1, 1, 2, 1><<<GRID, 512, 0, st>>>(cnt, idx, h_c, src_c, dst_c,
            dec_b_c, u_buf, h, proj_W, proj_b, out + (size_t)k * NB * NN, y_buf,
            nullptr, dec_W_ru, dec_a_ru, h_ru, src_ru, dst_ru, bq);
      else
        k_phaseA<1, 0, 1, 1><<<GRID, 512, 0, st>>>(cnt, idx, h_c, src_c, dst_c,
            dec_b_c, u_buf, h, proj_W, proj_b, out + (size_t)k * NB * NN, y_buf,
            nullptr, dec_W_ru, dec_a_ru, h_ru, src_ru, dst_ru, bq);
    }
  }

  // Join: main stream waits for all side quarters.
  for (int q = 0; q < NSTREAMS - 1; ++q) {
    hipEventRecord(evJoin[q], s2[q]);
    hipStreamWaitEvent(stream, evJoin[q], 0);
  }
}

// Round 15
// 762.824 us; speedup vs baseline: 1.0997x; 1.0997x over previous
//
#include <hip/hip_runtime.h>
#include <math.h>

// GARNN: graph-attention GRU, B=16, N=512, U=64, SEQ=12, HORIZON=12, all f32.
// R15 = R13 (759us best: two-stream batch halves, R7 kernels byte-identical)
// + one-dispatch STAGGER: stream B's chain waits on an event recorded after
// stream A's init dispatch. With alternating phase durations (~14/~19us) the
// offset de-synchronizes the two chains' dispatch boundaries, so B's
// mid-dispatch execution fills A's ramp/drain bubbles (and vice versa) for
// the whole run instead of both draining simultaneously.
// Dispatch-count evidence: R7=49/802, R13=98/759, R14=196/839 -> 98 is right.

#define NB 16
#define NN 512
#define NU 64
#define CAP 128   // neighbor-list capacity (Bin(511,0.1) max << 128)
#define WPB 8     // waves (=nodes) per block

#define AS1 __attribute__((address_space(1)))
#define AS3 __attribute__((address_space(3)))

__device__ __forceinline__ void ld_lds16(float* lds_uniform, const float* g_perlane) {
#if __has_builtin(__builtin_amdgcn_global_load_lds)
  __builtin_amdgcn_global_load_lds((const AS1 unsigned int*)g_perlane,
                                   (AS3 unsigned int*)lds_uniform, 16, 0, 0);
#else
  int lane = threadIdx.x & 63;
  *(float4*)(lds_uniform + lane * 4) = *(const float4*)(g_perlane);
#endif
}

// Async-stage TB bytes of weights into sW. Wave w handles chunks c = w, w+8, ...
__device__ __forceinline__ void stage_weights(float* sW, const float* W, int TB,
                                              int w, int lane) {
  for (int c = w; c * 1024 < TB; c += WPB) {
    int off = c * 1024 + lane * 16;
    if (off < TB)
      ld_lds16((float*)((char*)sW + c * 1024), (const float*)((const char*)W + off));
  }
}

__device__ __forceinline__ float rlane(float v, int l) {
  return __int_as_float(__builtin_amdgcn_readlane(__float_as_int(v), l));
}
__device__ __forceinline__ int rlane_i(int v, int l) {
  return __builtin_amdgcn_readlane(v, l);
}
__device__ __forceinline__ float wave_max(float v) {
  #pragma unroll
  for (int s = 1; s < 64; s <<= 1) v = fmaxf(v, __shfl_xor(v, s));
  return v;
}
__device__ __forceinline__ float wave_sum(float v) {
  #pragma unroll
  for (int s = 1; s < 64; s <<= 1) v += __shfl_xor(v, s);
  return v;
}
__device__ __forceinline__ void wave_sum2(float& x, float& y) {
  #pragma unroll
  for (int s = 1; s < 64; s <<= 1) { x += __shfl_xor(x, s); y += __shfl_xor(y, s); }
}
__device__ __forceinline__ float fast_rcp(float x) {
#if __has_builtin(__builtin_amdgcn_rcpf)
  return __builtin_amdgcn_rcpf(x);
#else
  return 1.0f / x;
#endif
}
__device__ __forceinline__ float sigmoid_f(float x) {
  return fast_rcp(1.0f + __expf(-x));
}
__device__ __forceinline__ float tanh_f(float x) {
  return 1.0f - 2.0f * fast_rcp(__expf(2.0f * x) + 1.0f);
}

// Half-grid decode (512 blocks, 8 batches): XCD x = bx&7 owns batch bhalf+x;
// node i = (bx>>3)*8 + wave. Bijective per half. Perf-only heuristic.
__device__ __forceinline__ void decode_half(int bx, int w, int bhalf,
                                            int& b, int& i) {
  b = bhalf + (bx & 7);
  i = (((bx >> 3)) << 3) | w;
}

// Neighbor lists: mask[i][j] = adj[i][j] > 0.9 || i == j, ascending j.
// Pad tail [cnt, CAP) with j=i so gather loops run unpredicated (p=0 there).
__global__ __launch_bounds__(64) void k_adj(const float* __restrict__ adj,
                                            int* __restrict__ cnt,
                                            int* __restrict__ idx) {
  int i = blockIdx.x;
  int l = threadIdx.x;
  int base = 0;
  #pragma unroll
  for (int c = 0; c < 8; ++c) {
    int j = c * 64 + l;
    bool pred = (adj[i * NN + j] > 0.9f) || (j == i);
    unsigned long long m = __ballot(pred);
    int pos = base + __popcll(m & ((1ull << l) - 1ull));
    if (pred && pos < CAP) idx[i * CAP + pos] = j;
    base += __popcll(m);
  }
  int total = base > CAP ? CAP : base;
  for (int p = total + l; p < CAP; p += 64) idx[i * CAP + p] = i;  // pad
  if (l == 0) cnt[i] = total;
}

// Phase B: ru-attention -> r,u ; write u; h_c = [x, r*h] @ W_c; src_c/dst_c.
// EXACT R7 structure (depth-16 gather, (512,6)); bhalf selects batch half.
template <int DIN>
__global__ __launch_bounds__(512, 6) void k_phaseB(
    const int* __restrict__ cnt, const int* __restrict__ idx,
    const float* __restrict__ h_ru, const float* __restrict__ src_ru,
    const float* __restrict__ dst_ru, const float* __restrict__ b_ru,
    const float* __restrict__ h, const float* __restrict__ x_ptr,
    const float* __restrict__ W_c, const float* __restrict__ a_c,
    float* __restrict__ h_c, float* __restrict__ src_c,
    float* __restrict__ dst_c, float* __restrict__ u_buf, int bhalf) {
  constexpr int TB = (DIN + NU) * NU * 4;
  __shared__ float sW[(DIN + NU) * NU];
  __shared__ float sh[WPB * NU];    // per-wave r*h broadcast
  const int tid = threadIdx.x;
  const int w = tid >> 6, lane = tid & 63;

  stage_weights(sW, W_c, TB, w, lane);   // async; drained at the barrier below

  int b, i;
  decode_half(blockIdx.x, w, bhalf, b, i);
  const int base_bi = (b << 9) + i;
  const float* __restrict__ hrb = h_ru + ((size_t)b << 16);
  const float* __restrict__ drb = dst_ru + (b << 9);

  const int c_ = cnt[i];
  const float si = src_ru[base_bi];
  const int j0 = idx[(i << 7) + lane];
  const int j1 = idx[(i << 7) + 64 + lane];
  float e0 = -1e30f, e1 = -1e30f;
  if (lane < c_)      { float t = si + drb[j0]; e0 = t >= 0.f ? t : 0.2f * t; }
  if (lane + 64 < c_) { float t = si + drb[j1]; e1 = t >= 0.f ? t : 0.2f * t; }
  float m = wave_max(fmaxf(e0, e1));
  float p0 = (lane < c_) ? __expf(e0 - m) : 0.f;
  float p1 = (lane + 64 < c_) ? __expf(e1 - m) : 0.f;
  float inv = fast_rcp(wave_sum(p0 + p1));
  p0 *= inv; p1 *= inv;

  const int g0 = lane << 1;
  float A0 = 0.f, A1 = 0.f, B0 = 0.f, B1 = 0.f;
  const int cc = (c_ + 15) & ~15;
  for (int base = 0; base < cc; base += 16) {
    float2 hv[16];
    #pragma unroll
    for (int q = 0; q < 16; ++q) {
      int jj = base + q;
      int sl = jj & 63;
      int j = (jj < 64) ? rlane_i(j0, sl) : rlane_i(j1, sl);
      hv[q] = *(const float2*)(hrb + (j << 7) + g0);
    }
    #pragma unroll
    for (int q = 0; q < 16; ++q) {
      int jj = base + q;
      int sl = jj & 63;
      float pv = (jj < 64) ? rlane(p0, sl) : rlane(p1, sl);
      if (q & 1) { B0 = fmaf(pv, hv[q].x, B0); B1 = fmaf(pv, hv[q].y, B1); }
      else       { A0 = fmaf(pv, hv[q].x, A0); A1 = fmaf(pv, hv[q].y, A1); }
    }
  }
  A0 += B0; A1 += B1;

  const float2 br = *(const float2*)(b_ru + g0);
  const float ru0 = sigmoid_f(A0 + br.x);
  const float ru1 = sigmoid_f(A1 + br.y);

  if (lane < 32) {
    float2 hh = *(const float2*)(h + ((size_t)base_bi << 6) + g0);
    *(float2*)&sh[(w << 6) + g0] = make_float2(ru0 * hh.x, ru1 * hh.y);
  } else {
    *(float2*)(u_buf + ((size_t)base_bi << 6) + (g0 - 64)) = make_float2(ru0, ru1);
  }

  __syncthreads();   // drains async weight stage + sh visibility

  float acc;
  if (DIN == 2) {
    float2 xv = *(const float2*)(x_ptr + ((size_t)base_bi << 1));
    acc = xv.x * sW[lane];
    acc = fmaf(xv.y, sW[NU + lane], acc);
  } else {
    acc = x_ptr[base_bi] * sW[lane];
  }
  const float* __restrict__ sWh = sW + DIN * NU;
  const float* shw = sh + (w << 6);
  #pragma unroll
  for (int f2 = 0; f2 < 32; ++f2) {
    float2 rv = *(const float2*)(shw + 2 * f2);   // b64 broadcast
    acc = fmaf(rv.x, sWh[(2 * f2) * NU + lane], acc);
    acc = fmaf(rv.y, sWh[(2 * f2 + 1) * NU + lane], acc);
  }
  h_c[((size_t)base_bi << 6) + lane] = acc;
  float s0 = acc * a_c[lane];
  float s1 = acc * a_c[NU + lane];
  wave_sum2(s0, s1);
  if (lane == 0) { src_c[base_bi] = s0; dst_c[base_bi] = s1; }
}

// Phase A: c-attention -> c; h_new = u*h + (1-u)*c (UPD) or 0 (init);
// OUT: proj -> out+y_buf; DIN_NEXT>0: next cell h_ru = [x_next, h_new] @ W_ru.
// EXACT R7 structure; bhalf selects batch half.
template <int UPD, int DIN_NEXT, int XMODE, int OUT>
__global__ __launch_bounds__(512, 6) void k_phaseA(
    const int* __restrict__ cnt, const int* __restrict__ idx,
    const float* __restrict__ h_c, const float* __restrict__ src_c,
    const float* __restrict__ dst_c, const float* __restrict__ b_c,
    const float* __restrict__ u_buf, float* __restrict__ h,
    const float* __restrict__ proj_W, const float* __restrict__ proj_b,
    float* __restrict__ out_slice, float* __restrict__ y_buf,
    const float* __restrict__ x_ptr,
    const float* __restrict__ W_ru, const float* __restrict__ a_ru,
    float* __restrict__ h_ru, float* __restrict__ src_ru,
    float* __restrict__ dst_ru, int bhalf) {
  constexpr int SWN = (DIN_NEXT > 0) ? (DIN_NEXT + NU) * 128 : 1;
  constexpr int TB = (DIN_NEXT > 0) ? SWN * 4 : 0;
  __shared__ float sW[SWN];
  __shared__ float sh[WPB * NU];
  const int tid = threadIdx.x;
  const int w = tid >> 6, lane = tid & 63;

  if (DIN_NEXT > 0) stage_weights(sW, W_ru, TB, w, lane);  // async

  int b, i;
  decode_half(blockIdx.x, w, bhalf, b, i);
  const int base_bi = (b << 9) + i;

  float hn = 0.f;
  if (UPD) {
    const float* __restrict__ hcb = h_c + ((size_t)b << 15);
    const float* __restrict__ dcb = dst_c + (b << 9);
    const int c_ = cnt[i];
    const float si = src_c[base_bi];
    const int j0 = idx[(i << 7) + lane];
    const int j1 = idx[(i << 7) + 64 + lane];
    float e0 = -1e30f, e1 = -1e30f;
    if (lane < c_)      { float t = si + dcb[j0]; e0 = t >= 0.f ? t : 0.2f * t; }
    if (lane + 64 < c_) { float t = si + dcb[j1]; e1 = t >= 0.f ? t : 0.2f * t; }
    float m = wave_max(fmaxf(e0, e1));
    float p0 = (lane < c_) ? __expf(e0 - m) : 0.f;
    float p1 = (lane + 64 < c_) ? __expf(e1 - m) : 0.f;
    float inv = fast_rcp(wave_sum(p0 + p1));
    p0 *= inv; p1 *= inv;

    float A = 0.f, Bacc = 0.f;
    const int cc = (c_ + 15) & ~15;
    for (int base = 0; base < cc; base += 16) {
      float hv[16];
      #pragma unroll
      for (int q = 0; q < 16; ++q) {
        int jj = base + q;
        int sl = jj & 63;
        int j = (jj < 64) ? rlane_i(j0, sl) : rlane_i(j1, sl);
        hv[q] = hcb[(j << 6) + lane];
      }
      #pragma unroll
      for (int q = 0; q < 16; ++q) {
        int jj = base + q;
        int sl = jj & 63;
        float pv = (jj < 64) ? rlane(p0, sl) : rlane(p1, sl);
        if (q & 1) Bacc = fmaf(pv, hv[q], Bacc);
        else       A = fmaf(pv, hv[q], A);
      }
    }
    A += Bacc;
    const float cc_ = tanh_f(A + b_c[lane]);
    const float u = u_buf[((size_t)base_bi << 6) + lane];
    const float ho = h[((size_t)base_bi << 6) + lane];
    hn = fmaf(u, ho - cc_, cc_);   // u*ho + (1-u)*cc
  }
  h[((size_t)base_bi << 6) + lane] = hn;
  sh[(w << 6) + lane] = hn;        // wave-private broadcast buffer

  float y = 0.f;
  if (OUT) {
    float t = wave_sum(hn * proj_W[lane]);
    y = t + proj_b[0];
    if (lane == 0) { out_slice[base_bi] = y; y_buf[base_bi] = y; }
  }

  if (DIN_NEXT > 0) {
    __syncthreads();   // drains async weight stage; sh written above
    const int g0 = lane << 1;
    float a0, a1;
    if (XMODE == 0) {
      if (DIN_NEXT == 2) {
        float2 xv = *(const float2*)(x_ptr + ((size_t)base_bi << 1));
        a0 = xv.x * sW[g0];
        a1 = xv.x * sW[g0 + 1];
        a0 = fmaf(xv.y, sW[128 + g0], a0);
        a1 = fmaf(xv.y, sW[128 + g0 + 1], a1);
      } else {
        float xv = x_ptr[base_bi];
        a0 = xv * sW[g0]; a1 = xv * sW[g0 + 1];
      }
    } else if (XMODE == 2) {
      a0 = y * sW[g0]; a1 = y * sW[g0 + 1];
    } else {  // XMODE==1: decoder GO token (zeros)
      a0 = 0.f; a1 = 0.f;
    }
    const float* __restrict__ sWh = sW + DIN_NEXT * 128;
    const float* shw = sh + (w << 6);
    #pragma unroll
    for (int f2 = 0; f2 < 32; ++f2) {
      float2 hp = *(const float2*)(shw + 2 * f2);          // b64 broadcast
      float2 w0 = *(const float2*)(sWh + (2 * f2) * 128 + g0);
      float2 w1 = *(const float2*)(sWh + (2 * f2 + 1) * 128 + g0);
      a0 = fmaf(hp.x, w0.x, a0); a1 = fmaf(hp.x, w0.y, a1);
      a0 = fmaf(hp.y, w1.x, a0); a1 = fmaf(hp.y, w1.y, a1);
    }
    *(float2*)(h_ru + ((size_t)base_bi << 7) + g0) = make_float2(a0, a1);
    const float2 ar0 = *(const float2*)(a_ru + g0);
    const float2 ar1 = *(const float2*)(a_ru + 128 + g0);
    float s0 = a0 * ar0.x + a1 * ar0.y;
    float s1 = a0 * ar1.x + a1 * ar1.y;
    wave_sum2(s0, s1);
    if (lane == 0) { src_ru[base_bi] = s0; dst_ru[base_bi] = s1; }
  }
}

extern "C" void kernel_launch(void* const* d_in, const int* in_sizes, int n_in,
                              void* d_out, int out_size, void* d_ws, size_t ws_size,
                              hipStream_t stream) {
  (void)in_sizes; (void)n_in; (void)out_size; (void)ws_size;
  const float* inputs   = (const float*)d_in[0];
  const float* adj      = (const float*)d_in[1];
  const float* enc_W_ru = (const float*)d_in[2];
  const float* enc_a_ru = (const float*)d_in[3];
  const float* enc_b_ru = (const float*)d_in[4];
  const float* enc_W_c  = (const float*)d_in[5];
  const float* enc_a_c  = (const float*)d_in[6];
  const float* enc_b_c  = (const float*)d_in[7];
  const float* dec_W_ru = (const float*)d_in[8];
  const float* dec_a_ru = (const float*)d_in[9];
  const float* dec_b_ru = (const float*)d_in[10];
  const float* dec_W_c  = (const float*)d_in[11];
  const float* dec_a_c  = (const float*)d_in[12];
  const float* dec_b_c  = (const float*)d_in[13];
  const float* proj_W   = (const float*)d_in[14];
  const float* proj_b   = (const float*)d_in[15];
  float* out = (float*)d_out;

  char* ws = (char*)d_ws;
  int*   cnt    = (int*)ws;                    // 512*4        = 2048
  int*   idx    = (int*)(ws + 2048);           // 512*128*4    = 262144
  float* h      = (float*)(ws + 264192);       // 16*512*64*4  = 2097152
  float* h_ru   = (float*)(ws + 2361344);      // 16*512*128*4 = 4194304
  float* src_ru = (float*)(ws + 6555648);      // 32768
  float* dst_ru = (float*)(ws + 6588416);      // 32768
  float* h_c    = (float*)(ws + 6621184);      // 2097152
  float* src_c  = (float*)(ws + 8718336);      // 32768
  float* dst_c  = (float*)(ws + 8751104);      // 32768
  float* u_buf  = (float*)(ws + 8783872);      // 2097152
  float* y_buf  = (float*)(ws + 10881024);     // 32768 (end 10913792)

  // One-time side-stream + events (resources only; no work-affecting state).
  static hipStream_t s2 = nullptr;
  static hipEvent_t evStag = nullptr, evJoin = nullptr;
  if (s2 == nullptr) {
    hipStreamCreateWithFlags(&s2, hipStreamNonBlocking);
    hipEventCreateWithFlags(&evStag, hipEventDisableTiming);
    hipEventCreateWithFlags(&evJoin, hipEventDisableTiming);
  }

  hipMemsetAsync(y_buf, 0, NB * NN * sizeof(float), stream);
  k_adj<<<NN, 64, 0, stream>>>(adj, cnt, idx);

  const int GRID = (NB * NN) / (2 * WPB);  // 512 blocks per half-dispatch

  // ---- stream A (half 0): init first, then record the stagger event ----
  k_phaseA<0, 2, 0, 0><<<GRID, 512, 0, stream>>>(cnt, idx, h_c, src_c, dst_c,
      enc_b_c, u_buf, h, proj_W, proj_b, nullptr, y_buf,
      inputs, enc_W_ru, enc_a_ru, h_ru, src_ru, dst_ru, 0);
  hipEventRecord(evStag, stream);
  // Stream B starts one dispatch late: boundaries de-synchronized thereafter.
  hipStreamWaitEvent(s2, evStag, 0);

  for (int half = 0; half < 2; ++half) {
    hipStream_t st = (half == 0) ? stream : s2;
    const int bh = half * 8;

    if (half == 1) {  // stream B's init (A's was launched above)
      k_phaseA<0, 2, 0, 0><<<GRID, 512, 0, st>>>(cnt, idx, h_c, src_c, dst_c,
          enc_b_c, u_buf, h, proj_W, proj_b, nullptr, y_buf,
          inputs, enc_W_ru, enc_a_ru, h_ru, src_ru, dst_ru, bh);
    }

    for (int t = 0; t < 12; ++t) {
      k_phaseB<2><<<GRID, 512, 0, st>>>(cnt, idx, h_ru, src_ru, dst_ru, enc_b_ru,
          h, inputs + (size_t)t * NB * NN * 2, enc_W_c, enc_a_c,
          h_c, src_c, dst_c, u_buf, bh);
      if (t < 11)
        k_phaseA<1, 2, 0, 0><<<GRID, 512, 0, st>>>(cnt, idx, h_c, src_c, dst_c,
            enc_b_c, u_buf, h, proj_W, proj_b, nullptr, y_buf,
            inputs + (size_t)(t + 1) * NB * NN * 2, enc_W_ru, enc_a_ru,
            h_ru, src_ru, dst_ru, bh);
      else  // last encoder cell: prepare decoder cell 0 (x = GO = zeros)
        k_phaseA<1, 1, 1, 0><<<GRID, 512, 0, st>>>(cnt, idx, h_c, src_c, dst_c,
            enc_b_c, u_buf, h, proj_W, proj_b, nullptr, y_buf,
            nullptr, dec_W_ru, dec_a_ru, h_ru, src_ru, dst_ru, bh);
    }

    for (int k = 0; k < 12; ++k) {
      k_phaseB<1><<<GRID, 512, 0, st>>>(cnt, idx, h_ru, src_ru, dst_ru, dec_b_ru,
          h, y_buf, dec_W_c, dec_a_c, h_c, src_c, dst_c, u_buf, bh);
      if (k < 11)
        k_phaseA<1, 1, 2, 1><<<GRID, 512, 0, st>>>(cnt, idx, h_c, src_c, dst_c,
            dec_b_c, u_buf, h, proj_W, proj_b, out + (size_t)k * NB * NN, y_buf,
            nullptr, dec_W_ru, dec_a_ru, h_ru, src_ru, dst_ru, bh);
      else
        k_phaseA<1, 0, 1, 1><<<GRID, 512, 0, st>>>(cnt, idx, h_c, src_c, dst_c,
            dec_b_c, u_buf, h, proj_W, proj_b, out + (size_t)k * NB * NN, y_buf,
            nullptr, dec_W_ru, dec_a_ru, h_ru, src_ru, dst_ru, bh);
    }
  }

  // Join: main stream waits for the side half before kernel_launch returns.
  hipEventRecord(evJoin, s2);
  hipStreamWaitEvent(stream, evJoin, 0);
}